// Round 1
// baseline (1506.266 us; speedup 1.0000x reference)
//
#include <hip/hip_runtime.h>

typedef __attribute__((ext_vector_type(4))) float f32x4;
typedef __attribute__((ext_vector_type(8))) short s16x8;

// ---- LDS layout (byte offsets), total 131072 = 128 KiB ----
#define L_XW   0        // bf16 [64][256] swz, stride 512B (later: H chunk, later mlp f32 low)
#define L_O    32768    // bf16 [64][256] swz, stride 512B (later: mlp f32 high)
#define L_QKV2 65536    // bf16 [64][128] swz, stride 256B (q|k for head pair)
#define L_VT   81920    // bf16 [2][32][64] swz, stride 128B (v transposed per head)
#define L_P    90112    // bf16 [64][64] swz, stride 128B
#define L_Y    65536    // f32 [64][256] swz, stride 1024B (aliases QKV2/VT/P after attention)
#define L_MLP  0        // f32 [64][256] swz, stride 1024B (aliases XW+O in epilogue)
#define SMEM_BYTES 131072

// ---- workspace layout (byte offsets) ----
#define WSO_BIAS   0         // f32 [8][64][64]            131072 B
#define WSO_QKVW   131072    // bf16 [48][32][16][8]       393216 B
#define WSO_PROJW  524288    // bf16 [16][32][16][8]       131072 B
#define WSO_FC1W   655360    // bf16 [64][32][16][8]       524288 B
#define WSO_FC2W   1179648   // bf16 [16][128][16][8]      524288 B  (ends 1703936)

__device__ __forceinline__ unsigned short f2bf(float f) {
  union { float f; unsigned u; } v; v.f = f;
  unsigned r = v.u + 0x7FFFu + ((v.u >> 16) & 1u);
  return (unsigned short)(r >> 16);
}
__device__ __forceinline__ float bf2f(unsigned short b) {
  union { unsigned u; float f; } v; v.u = ((unsigned)b) << 16;
  return v.f;
}
__device__ __forceinline__ int swzb(int row, int byteoff) {
  return byteoff ^ ((row & 7) << 4);
}

// ---------------- prep: pack all weights to bf16 MFMA-fragment layout ----------------
// dst[((nt*(K/8)+kg)*16+c)*8+j] = bf16(src[(kg*8+j)*N + nt*16 + c])
__global__ void prep_pack_kernel(const float* __restrict__ qkv_w,
                                 const float* __restrict__ proj_w,
                                 const float* __restrict__ fc1_w,
                                 const float* __restrict__ fc2_w,
                                 unsigned char* __restrict__ wsb) {
  int e = blockIdx.x * 256 + threadIdx.x;   // 0 .. 786431
  const float* src; unsigned short* dst; int K, N; int eo;
  if (e < 196608)       { eo = e;          src = qkv_w;  dst = (unsigned short*)(wsb + WSO_QKVW);  K = 256;  N = 768; }
  else if (e < 262144)  { eo = e - 196608; src = proj_w; dst = (unsigned short*)(wsb + WSO_PROJW); K = 256;  N = 256; }
  else if (e < 524288)  { eo = e - 262144; src = fc1_w;  dst = (unsigned short*)(wsb + WSO_FC1W);  K = 256;  N = 1024; }
  else                  { eo = e - 524288; src = fc2_w;  dst = (unsigned short*)(wsb + WSO_FC2W);  K = 1024; N = 256; }
  int j = eo & 7, c = (eo >> 3) & 15, rest = eo >> 7;
  int Kg = K >> 3;
  int kg = rest % Kg, nt = rest / Kg;
  dst[eo] = f2bf(src[(kg * 8 + j) * N + nt * 16 + c]);
}

// ---------------- prep: relative-position-bias table via CPB MLP ----------------
__global__ void prep_bias_kernel(const float* __restrict__ cpb_w1,
                                 const float* __restrict__ cpb_b1,
                                 const float* __restrict__ cpb_w2,
                                 unsigned char* __restrict__ wsb) {
  __shared__ float bt[225][8];
  int tid = threadIdx.x;
  for (int t = tid; t < 225; t += 256) {
    int a = t / 15, b = t % 15;
    float r0 = (float)(a - 7) * (8.0f / 7.0f);
    float r1 = (float)(b - 7) * (8.0f / 7.0f);
    float f0 = (r0 >= 0.f ? 1.f : -1.f) * log2f(fabsf(r0) + 1.f) * (1.f / 3.f);
    float f1 = (r1 >= 0.f ? 1.f : -1.f) * log2f(fabsf(r1) + 1.f) * (1.f / 3.f);
    float acc[8] = {0.f,0.f,0.f,0.f,0.f,0.f,0.f,0.f};
    for (int k = 0; k < 512; ++k) {
      float hv = f0 * cpb_w1[k] + f1 * cpb_w1[512 + k] + cpb_b1[k];
      hv = fmaxf(hv, 0.f);
      #pragma unroll
      for (int h = 0; h < 8; ++h) acc[h] += hv * cpb_w2[k * 8 + h];
    }
    #pragma unroll
    for (int h = 0; h < 8; ++h) bt[t][h] = acc[h];
  }
  __syncthreads();
  float* biasp = (float*)(wsb + WSO_BIAS);
  for (int e = tid; e < 32768; e += 256) {
    int h = e >> 12, rem = e & 4095, i = rem >> 6, j = rem & 63;
    int dr = (i >> 3) - (j >> 3) + 7, dc = (i & 7) - (j & 7) + 7;
    float v = bt[dr * 15 + dc][h];
    biasp[e] = 16.f / (1.f + expf(-v));
  }
}

// ---------------- main fused per-window kernel ----------------
__global__ __launch_bounds__(256, 1)
void swin_block_kernel(const float* __restrict__ x,
                       const float* __restrict__ ls,
                       const float* __restrict__ proj_b,
                       const float* __restrict__ ln1w, const float* __restrict__ ln1b,
                       const float* __restrict__ fc1b,
                       const float* __restrict__ fc2b,
                       const float* __restrict__ ln2w, const float* __restrict__ ln2b,
                       const unsigned char* __restrict__ wsb,
                       float* __restrict__ out) {
  extern __shared__ char sm[];
  const int tid = threadIdx.x;
  const int w = tid >> 6;
  const int lane = tid & 63;
  const int g = lane >> 4;
  const int c16 = lane & 15;

  const int blk = blockIdx.x;
  const int bb = blk >> 10;
  const int widx = blk & 1023;
  const int wi = widx >> 5, wj = widx & 31;

  const float* bias = (const float*)(wsb + WSO_BIAS);
  const unsigned short* qkvw = (const unsigned short*)(wsb + WSO_QKVW);
  const unsigned short* projw = (const unsigned short*)(wsb + WSO_PROJW);
  const unsigned short* fc1w = (const unsigned short*)(wsb + WSO_FC1W);
  const unsigned short* fc2w = (const unsigned short*)(wsb + WSO_FC2W);

  // ---------- Phase 1: load shifted window -> XW (bf16, swizzled) ----------
  for (int it = 0; it < 16; ++it) {
    int f = tid + it * 256;              // 0..4095 float4 units
    int c = f >> 4;
    int u = f & 15;
    int tr = u >> 1, tc4 = (u & 1) * 4;
    int rp = (wi * 8 + tr + 4) & 255;
    int cp = (wj * 8 + tc4 + 4) & 255;
    const float4 v = *(const float4*)(x + ((((size_t)bb * 256 + c) * 256 + rp) * 256 + cp));
    int t0 = tr * 8 + tc4;
    float vv[4] = {v.x, v.y, v.z, v.w};
    #pragma unroll
    for (int e = 0; e < 4; ++e) {
      int t = t0 + e;
      *(unsigned short*)(sm + L_XW + t * 512 + swzb(t, c * 2)) = f2bf(vv[e]);
    }
  }
  __syncthreads();

  // ---------- Phase 2-4: attention per head pair ----------
  for (int hp = 0; hp < 4; ++hp) {
    // qkv GEMM for heads 2hp, 2hp+1: 12 N-tiles, wave w -> tiles w*3..w*3+2
    f32x4 acc[3][4];
    #pragma unroll
    for (int a = 0; a < 3; ++a)
      #pragma unroll
      for (int b = 0; b < 4; ++b) acc[a][b] = f32x4{0.f,0.f,0.f,0.f};
    int gtile[3];
    #pragma unroll
    for (int tl = 0; tl < 3; ++tl) {
      int local = w * 3 + tl;
      int qi = local >> 2, hh = (local >> 1) & 1, dt = local & 1;
      gtile[tl] = qi * 16 + (2 * hp + hh) * 2 + dt;
    }
    for (int k0 = 0; k0 < 256; k0 += 32) {
      s16x8 af[4];
      #pragma unroll
      for (int mt = 0; mt < 4; ++mt) {
        int row = mt * 16 + c16;
        af[mt] = *(const s16x8*)(sm + L_XW + row * 512 + swzb(row, (k0 + g * 8) * 2));
      }
      #pragma unroll
      for (int tl = 0; tl < 3; ++tl) {
        s16x8 bfr = *(const s16x8*)(qkvw + ((gtile[tl] * 32 + (k0 >> 3) + g) * 16 + c16) * 8);
        #pragma unroll
        for (int mt = 0; mt < 4; ++mt)
          acc[tl][mt] = __builtin_amdgcn_mfma_f32_16x16x32_bf16(af[mt], bfr, acc[tl][mt], 0, 0, 0);
      }
    }
    // epilogue: q,k -> QKV2 raw; v -> VT transposed
    #pragma unroll
    for (int tl = 0; tl < 3; ++tl) {
      int local = w * 3 + tl;
      #pragma unroll
      for (int mt = 0; mt < 4; ++mt)
        #pragma unroll
        for (int r = 0; r < 4; ++r) {
          int i = mt * 16 + 4 * g + r;
          unsigned short bv = f2bf(acc[tl][mt][r]);
          if (local < 8) {
            *(unsigned short*)(sm + L_QKV2 + i * 256 + swzb(i, (local * 16 + c16) * 2)) = bv;
          } else {
            int hh = (local - 8) >> 1, dt = (local - 8) & 1;
            int d = dt * 16 + c16;
            *(unsigned short*)(sm + L_VT + hh * 4096 + d * 128 + swzb(d, i * 2)) = bv;
          }
        }
    }
    __syncthreads();

    // cosine-normalize q (with logit scale) and k, in place
    {
      int t = tid >> 2, sel = tid & 3;
      int qi = sel >> 1, hh = sel & 1;
      int colbase = qi * 64 + hh * 32;
      float vals[32];
      float ss = 0.f;
      #pragma unroll
      for (int b = 0; b < 4; ++b) {
        s16x8 vb = *(const s16x8*)(sm + L_QKV2 + t * 256 + swzb(t, colbase * 2 + b * 16));
        #pragma unroll
        for (int e = 0; e < 8; ++e) { float fv = bf2f((unsigned short)vb[e]); vals[b*8+e] = fv; ss += fv * fv; }
      }
      float scale = 1.f;
      if (qi == 0) scale = __expf(fminf(ls[2 * hp + hh], 4.6051702f));
      float inv = scale / fmaxf(sqrtf(ss), 1e-12f);
      #pragma unroll
      for (int b = 0; b < 4; ++b) {
        s16x8 vb;
        #pragma unroll
        for (int e = 0; e < 8; ++e) vb[e] = (short)f2bf(vals[b*8+e] * inv);
        *(s16x8*)(sm + L_QKV2 + t * 256 + swzb(t, colbase * 2 + b * 16)) = vb;
      }
    }
    __syncthreads();

    #pragma unroll 1
    for (int hh = 0; hh < 2; ++hh) {
      int h = 2 * hp + hh;
      // S = qn @ kn^T (wave w owns rows 16w..16w+15, all 4 col tiles)
      int arow = 16 * w + c16;
      s16x8 aq = *(const s16x8*)(sm + L_QKV2 + arow * 256 + swzb(arow, hh * 64 + g * 16));
      f32x4 s[4];
      #pragma unroll
      for (int nt = 0; nt < 4; ++nt) {
        int brow = nt * 16 + c16;
        s16x8 bk = *(const s16x8*)(sm + L_QKV2 + brow * 256 + swzb(brow, 128 + hh * 64 + g * 16));
        s[nt] = __builtin_amdgcn_mfma_f32_16x16x32_bf16(aq, bk, f32x4{0.f,0.f,0.f,0.f}, 0, 0, 0);
      }
      // bias + shift mask + softmax (in-register, 16-lane shfl reduce)
      int labi[4], labj[4];
      #pragma unroll
      for (int r = 0; r < 4; ++r) {
        int i = 16 * w + 4 * g + r;
        int tr = i >> 3, tc = i & 7;
        labi[r] = ((wi == 31) ? (tr >= 4 ? 2 : 1) : 0) * 3 + ((wj == 31) ? (tc >= 4 ? 2 : 1) : 0);
      }
      #pragma unroll
      for (int nt = 0; nt < 4; ++nt) {
        int j = nt * 16 + c16;
        int tr = j >> 3, tc = j & 7;
        labj[nt] = ((wi == 31) ? (tr >= 4 ? 2 : 1) : 0) * 3 + ((wj == 31) ? (tc >= 4 ? 2 : 1) : 0);
      }
      float p[4][4];
      #pragma unroll
      for (int r = 0; r < 4; ++r) {
        int i = 16 * w + 4 * g + r;
        float mx = -1e30f;
        float vv[4];
        #pragma unroll
        for (int nt = 0; nt < 4; ++nt) {
          int j = nt * 16 + c16;
          float v = s[nt][r] + bias[(h * 64 + i) * 64 + j];
          if (labi[r] != labj[nt]) v -= 100.f;
          vv[nt] = v;
          mx = fmaxf(mx, v);
        }
        mx = fmaxf(mx, __shfl_xor(mx, 1));
        mx = fmaxf(mx, __shfl_xor(mx, 2));
        mx = fmaxf(mx, __shfl_xor(mx, 4));
        mx = fmaxf(mx, __shfl_xor(mx, 8));
        float sum = 0.f;
        #pragma unroll
        for (int nt = 0; nt < 4; ++nt) { vv[nt] = __expf(vv[nt] - mx); sum += vv[nt]; }
        sum += __shfl_xor(sum, 1);
        sum += __shfl_xor(sum, 2);
        sum += __shfl_xor(sum, 4);
        sum += __shfl_xor(sum, 8);
        float inv = 1.f / sum;
        #pragma unroll
        for (int nt = 0; nt < 4; ++nt) p[nt][r] = vv[nt] * inv;
      }
      #pragma unroll
      for (int nt = 0; nt < 4; ++nt)
        #pragma unroll
        for (int r = 0; r < 4; ++r) {
          int i = 16 * w + 4 * g + r;
          int j = nt * 16 + c16;
          *(unsigned short*)(sm + L_P + i * 128 + swzb(i, j * 2)) = f2bf(p[nt][r]);
        }
      __syncthreads();
      // O_head = P @ V  (wave w: rows 16w.., 2 col tiles, K=64)
      f32x4 oacc[2] = {f32x4{0.f,0.f,0.f,0.f}, f32x4{0.f,0.f,0.f,0.f}};
      #pragma unroll
      for (int k0 = 0; k0 < 64; k0 += 32) {
        int prow = 16 * w + c16;
        s16x8 pa = *(const s16x8*)(sm + L_P + prow * 128 + swzb(prow, (k0 + g * 8) * 2));
        #pragma unroll
        for (int nt = 0; nt < 2; ++nt) {
          int vrow = nt * 16 + c16;
          s16x8 vb = *(const s16x8*)(sm + L_VT + hh * 4096 + vrow * 128 + swzb(vrow, (k0 + g * 8) * 2));
          oacc[nt] = __builtin_amdgcn_mfma_f32_16x16x32_bf16(pa, vb, oacc[nt], 0, 0, 0);
        }
      }
      #pragma unroll
      for (int nt = 0; nt < 2; ++nt)
        #pragma unroll
        for (int r = 0; r < 4; ++r) {
          int i = 16 * w + 4 * g + r;
          int col = h * 32 + nt * 16 + c16;
          *(unsigned short*)(sm + L_O + i * 512 + swzb(i, col * 2)) = f2bf(oacc[nt][r]);
        }
      __syncthreads();
    }
  }

  // ---------- Phase 5: proj -> Y (pre-LN, +proj_b) ----------
  {
    f32x4 accp[4][4];
    #pragma unroll
    for (int a = 0; a < 4; ++a)
      #pragma unroll
      for (int b = 0; b < 4; ++b) accp[a][b] = f32x4{0.f,0.f,0.f,0.f};
    for (int k0 = 0; k0 < 256; k0 += 32) {
      s16x8 af[4];
      #pragma unroll
      for (int mt = 0; mt < 4; ++mt) {
        int row = mt * 16 + c16;
        af[mt] = *(const s16x8*)(sm + L_O + row * 512 + swzb(row, (k0 + g * 8) * 2));
      }
      #pragma unroll
      for (int nt = 0; nt < 4; ++nt) {
        int gt = w * 4 + nt;
        s16x8 bfr = *(const s16x8*)(projw + ((gt * 32 + (k0 >> 3) + g) * 16 + c16) * 8);
        #pragma unroll
        for (int mt = 0; mt < 4; ++mt)
          accp[nt][mt] = __builtin_amdgcn_mfma_f32_16x16x32_bf16(af[mt], bfr, accp[nt][mt], 0, 0, 0);
      }
    }
    __syncthreads();   // all P/QKV2/VT reads done before Y (aliased region) is written
    #pragma unroll
    for (int nt = 0; nt < 4; ++nt) {
      int col = w * 64 + nt * 16 + c16;
      float pb = proj_b[col];
      #pragma unroll
      for (int mt = 0; mt < 4; ++mt)
        #pragma unroll
        for (int r = 0; r < 4; ++r) {
          int i = mt * 16 + 4 * g + r;
          *(float*)(sm + L_Y + i * 1024 + swzb(i, col * 4)) = accp[nt][mt][r] + pb;
        }
    }
  }
  __syncthreads();

  // ---------- LN1 + residual (y = LN(o)*g+b + xw), in place on Y ----------
  {
    int t = tid >> 2, q4 = tid & 3;
    float v[64];
    float s1 = 0.f;
    #pragma unroll
    for (int b2 = 0; b2 < 16; ++b2) {
      float4 fv = *(const float4*)(sm + L_Y + t * 1024 + swzb(t, q4 * 256 + b2 * 16));
      v[b2*4+0] = fv.x; v[b2*4+1] = fv.y; v[b2*4+2] = fv.z; v[b2*4+3] = fv.w;
      s1 += fv.x + fv.y + fv.z + fv.w;
    }
    s1 += __shfl_xor(s1, 1);
    s1 += __shfl_xor(s1, 2);
    float mu = s1 * (1.f / 256.f);
    float s2 = 0.f;
    #pragma unroll
    for (int e = 0; e < 64; ++e) { float d = v[e] - mu; s2 += d * d; }
    s2 += __shfl_xor(s2, 1);
    s2 += __shfl_xor(s2, 2);
    float rs = rsqrtf(s2 * (1.f / 256.f) + 1e-5f);
    #pragma unroll
    for (int e = 0; e < 64; ++e) {
      int c = q4 * 64 + e;
      float xwv = bf2f(*(const unsigned short*)(sm + L_XW + t * 512 + swzb(t, c * 2)));
      float yv = (v[e] - mu) * rs * ln1w[c] + ln1b[c] + xwv;
      *(float*)(sm + L_Y + t * 1024 + swzb(t, c * 4)) = yv;
    }
  }
  __syncthreads();

  // ---------- MLP: fc1(gelu) in 4 chunks, fc2 accumulated in registers ----------
  f32x4 acc2[4][4];
  #pragma unroll
  for (int a = 0; a < 4; ++a)
    #pragma unroll
    for (int b = 0; b < 4; ++b) acc2[a][b] = f32x4{0.f,0.f,0.f,0.f};

  for (int cc = 0; cc < 4; ++cc) {
    f32x4 acc1[4][4];
    #pragma unroll
    for (int a = 0; a < 4; ++a)
      #pragma unroll
      for (int b = 0; b < 4; ++b) acc1[a][b] = f32x4{0.f,0.f,0.f,0.f};
    for (int k0 = 0; k0 < 256; k0 += 32) {
      s16x8 af[4];
      #pragma unroll
      for (int mt = 0; mt < 4; ++mt) {
        int row = mt * 16 + c16;
        float4 fa = *(const float4*)(sm + L_Y + row * 1024 + swzb(row, (k0 + g * 8) * 4));
        float4 fb = *(const float4*)(sm + L_Y + row * 1024 + swzb(row, (k0 + g * 8) * 4 + 16));
        s16x8 t8;
        t8[0] = (short)f2bf(fa.x); t8[1] = (short)f2bf(fa.y); t8[2] = (short)f2bf(fa.z); t8[3] = (short)f2bf(fa.w);
        t8[4] = (short)f2bf(fb.x); t8[5] = (short)f2bf(fb.y); t8[6] = (short)f2bf(fb.z); t8[7] = (short)f2bf(fb.w);
        af[mt] = t8;
      }
      #pragma unroll
      for (int nt = 0; nt < 4; ++nt) {
        int gt = cc * 16 + w * 4 + nt;
        s16x8 bfr = *(const s16x8*)(fc1w + ((gt * 32 + (k0 >> 3) + g) * 16 + c16) * 8);
        #pragma unroll
        for (int mt = 0; mt < 4; ++mt)
          acc1[nt][mt] = __builtin_amdgcn_mfma_f32_16x16x32_bf16(af[mt], bfr, acc1[nt][mt], 0, 0, 0);
      }
    }
    // gelu + store H (aliases XW region; XW dead after LN1)
    #pragma unroll
    for (int nt = 0; nt < 4; ++nt) {
      int coll = w * 64 + nt * 16 + c16;
      float b1v = fc1b[cc * 256 + coll];
      #pragma unroll
      for (int mt = 0; mt < 4; ++mt)
        #pragma unroll
        for (int r = 0; r < 4; ++r) {
          int i = mt * 16 + 4 * g + r;
          float vv2 = acc1[nt][mt][r] + b1v;
          float ge = 0.5f * vv2 * (1.f + erff(vv2 * 0.70710678f));
          *(unsigned short*)(sm + L_XW + i * 512 + swzb(i, coll * 2)) = f2bf(ge);
        }
    }
    __syncthreads();
    // fc2 partial: acc2 += H_chunk @ fc2[cc*256.., :]
    for (int k0 = 0; k0 < 256; k0 += 32) {
      s16x8 af[4];
      #pragma unroll
      for (int mt = 0; mt < 4; ++mt) {
        int row = mt * 16 + c16;
        af[mt] = *(const s16x8*)(sm + L_XW + row * 512 + swzb(row, (k0 + g * 8) * 2));
      }
      #pragma unroll
      for (int nt = 0; nt < 4; ++nt) {
        int gt = w * 4 + nt;
        int kg = cc * 32 + (k0 >> 3) + g;
        s16x8 bfr = *(const s16x8*)(fc2w + ((gt * 128 + kg) * 16 + c16) * 8);
        #pragma unroll
        for (int mt = 0; mt < 4; ++mt)
          acc2[nt][mt] = __builtin_amdgcn_mfma_f32_16x16x32_bf16(af[mt], bfr, acc2[nt][mt], 0, 0, 0);
      }
    }
    __syncthreads();
  }

  // ---------- fc2 epilogue -> MLP f32 buffer (aliases XW+O) ----------
  #pragma unroll
  for (int nt = 0; nt < 4; ++nt) {
    int col = w * 64 + nt * 16 + c16;
    float b2v = fc2b[col];
    #pragma unroll
    for (int mt = 0; mt < 4; ++mt)
      #pragma unroll
      for (int r = 0; r < 4; ++r) {
        int i = mt * 16 + 4 * g + r;
        *(float*)(sm + L_MLP + i * 1024 + swzb(i, col * 4)) = acc2[nt][mt][r] + b2v;
      }
  }
  __syncthreads();

  // ---------- LN2 + residual (y2 = LN(mlp)*g+b + y), in place on MLP ----------
  {
    int t = tid >> 2, q4 = tid & 3;
    float v[64];
    float s1 = 0.f;
    #pragma unroll
    for (int b2 = 0; b2 < 16; ++b2) {
      float4 fv = *(const float4*)(sm + L_MLP + t * 1024 + swzb(t, q4 * 256 + b2 * 16));
      v[b2*4+0] = fv.x; v[b2*4+1] = fv.y; v[b2*4+2] = fv.z; v[b2*4+3] = fv.w;
      s1 += fv.x + fv.y + fv.z + fv.w;
    }
    s1 += __shfl_xor(s1, 1);
    s1 += __shfl_xor(s1, 2);
    float mu = s1 * (1.f / 256.f);
    float s2 = 0.f;
    #pragma unroll
    for (int e = 0; e < 64; ++e) { float d = v[e] - mu; s2 += d * d; }
    s2 += __shfl_xor(s2, 1);
    s2 += __shfl_xor(s2, 2);
    float rs = rsqrtf(s2 * (1.f / 256.f) + 1e-5f);
    #pragma unroll
    for (int e = 0; e < 64; ++e) {
      int c = q4 * 64 + e;
      float yres = *(const float*)(sm + L_Y + t * 1024 + swzb(t, c * 4));
      float yv = (v[e] - mu) * rs * ln2w[c] + ln2b[c] + yres;
      *(float*)(sm + L_MLP + t * 1024 + swzb(t, c * 4)) = yv;
    }
  }
  __syncthreads();

  // ---------- output: window reverse + un-shift (float4 stores) ----------
  for (int it = 0; it < 16; ++it) {
    int f = tid + it * 256;
    int c = f >> 4;
    int u = f & 15;
    int tr = u >> 1, tc4 = (u & 1) * 4;
    float tmp[4];
    #pragma unroll
    for (int e = 0; e < 4; ++e) {
      int t = tr * 8 + tc4 + e;
      tmp[e] = *(const float*)(sm + L_MLP + t * 1024 + swzb(t, c * 4));
    }
    float4 vv; vv.x = tmp[0]; vv.y = tmp[1]; vv.z = tmp[2]; vv.w = tmp[3];
    int rp = (wi * 8 + tr + 4) & 255;
    int cp = (wj * 8 + tc4 + 4) & 255;
    *(float4*)(out + ((((size_t)bb * 256 + c) * 256 + rp) * 256 + cp)) = vv;
  }
}

extern "C" void kernel_launch(void* const* d_in, const int* in_sizes, int n_in,
                              void* d_out, int out_size, void* d_ws, size_t ws_size,
                              hipStream_t stream) {
  const float* x      = (const float*)d_in[0];
  const float* qkv_w  = (const float*)d_in[1];
  const float* ls     = (const float*)d_in[2];
  const float* proj_w = (const float*)d_in[3];
  const float* proj_b = (const float*)d_in[4];
  const float* ln1w   = (const float*)d_in[5];
  const float* ln1b   = (const float*)d_in[6];
  const float* fc1_w  = (const float*)d_in[7];
  const float* fc1b   = (const float*)d_in[8];
  const float* fc2_w  = (const float*)d_in[9];
  const float* fc2b   = (const float*)d_in[10];
  const float* ln2w   = (const float*)d_in[11];
  const float* ln2b   = (const float*)d_in[12];
  const float* cpb_w1 = (const float*)d_in[13];
  const float* cpb_b1 = (const float*)d_in[14];
  const float* cpb_w2 = (const float*)d_in[15];
  unsigned char* wsb = (unsigned char*)d_ws;
  float* out = (float*)d_out;

  hipFuncSetAttribute(reinterpret_cast<const void*>(swin_block_kernel),
                      hipFuncAttributeMaxDynamicSharedMemorySize, SMEM_BYTES);

  prep_pack_kernel<<<3072, 256, 0, stream>>>(qkv_w, proj_w, fc1_w, fc2_w, wsb);
  prep_bias_kernel<<<1, 256, 0, stream>>>(cpb_w1, cpb_b1, cpb_w2, wsb);
  swin_block_kernel<<<2048, 256, SMEM_BYTES, stream>>>(
      x, ls, proj_b, ln1w, ln1b, fc1b, fc2b, ln2w, ln2b, wsb, out);
}